// Round 1
// baseline (471.132 us; speedup 1.0000x reference)
//
#include <hip/hip_runtime.h>
#include <hip/hip_bf16.h>

typedef unsigned short u16;
typedef __bf16 bf16x8 __attribute__((ext_vector_type(8)));
typedef float f32x4 __attribute__((ext_vector_type(4)));

#define CH 128
#define NB 32
#define NH 4
#define HD 32
#define SCALE_F 0.17677669529663687f

__device__ __forceinline__ u16 f2b(float f) {
  union { float f; unsigned u; } v; v.f = f;
  unsigned r = v.u + 0x7fffu + ((v.u >> 16) & 1u);
  return (u16)(r >> 16);
}

// ---------------------------------------------------------------- prep ----
__global__ void prep_kernel(const float* __restrict__ qw, const float* __restrict__ ow,
                            u16* __restrict__ wq, u16* __restrict__ wo,
                            float* __restrict__ stats) {
  int t = blockIdx.x * 256 + threadIdx.x;           // 192 blocks -> 49152 threads
  if (t < 49152) wq[t] = f2b(qw[t]);
  if (t < 16384) wo[t] = f2b(ow[t]);
  if (t < 8192)  stats[t] = 0.0f;
}

// ------------------------------------------------------------ main pass ---
// 1 block = 1 sample. 4 waves. LDS ~44KB -> 3 blocks/CU.
__global__ __launch_bounds__(256, 3) void attn_kernel(
    const float* __restrict__ x, const u16* __restrict__ wq,
    const float* __restrict__ qkv_b, const u16* __restrict__ wo,
    const float* __restrict__ out_b, const float* __restrict__ rel,
    float* __restrict__ out, float* __restrict__ stats) {

  __shared__ __attribute__((aligned(16))) u16 sXt[32 * 128];    // x^T bf16; aliased as O^T later
  __shared__ __attribute__((aligned(16))) u16 sQKt[32 * 256];   // [n][o<256] q,k transposed
  __shared__ __attribute__((aligned(16))) u16 sVn[128 * 40];    // [h*32+d][m] padded rows
  __shared__ __attribute__((aligned(16))) u16 sP[4 * 32 * 40];  // per-wave P

  const int tid = threadIdx.x;
  const int w    = tid >> 6;
  const int lane = tid & 63;
  const int g    = lane >> 4;
  const int l15  = lane & 15;
  const int b    = blockIdx.x;
  const float* xb = x + (size_t)b * (CH * NB);

  // ---- stage x[b] (f32 [128][32]) -> sXt bf16 [n][c], XOR-swizzled
  #pragma unroll
  for (int it = 0; it < 4; ++it) {
    int id = it * 256 + tid;                 // 0..1023 float4s
    int c = id >> 3, n4 = id & 7;
    const float4 v = *(const float4*)(xb + c * NB + n4 * 4);
    float vv[4] = {v.x, v.y, v.z, v.w};
    #pragma unroll
    for (int j = 0; j < 4; ++j) {
      int n = n4 * 4 + j;
      sXt[(n * 128 + c) ^ ((n & 7) << 3)] = f2b(vv[j]);
    }
  }
  __syncthreads();

  // ---- phase 1: QKV[384][32] = Wq * X  (+qkv_b at store)
  {
    f32x4 acc[6][2];
    #pragma unroll
    for (int mi = 0; mi < 6; ++mi)
      #pragma unroll
      for (int ct = 0; ct < 2; ++ct)
        acc[mi][ct] = (f32x4){0.f, 0.f, 0.f, 0.f};

    #pragma unroll
    for (int kk = 0; kk < 4; ++kk) {
      bf16x8 bfr[2];
      #pragma unroll
      for (int ct = 0; ct < 2; ++ct) {
        int n = ct * 16 + l15;
        bfr[ct] = *(const bf16x8*)&sXt[(n * 128 + kk * 32 + 8 * g) ^ ((n & 7) << 3)];
      }
      #pragma unroll
      for (int mi = 0; mi < 6; ++mi) {
        int row = 96 * w + mi * 16 + l15;
        bf16x8 afr = *(const bf16x8*)&wq[row * 128 + kk * 32 + 8 * g];
        acc[mi][0] = __builtin_amdgcn_mfma_f32_16x16x32_bf16(afr, bfr[0], acc[mi][0], 0, 0, 0);
        acc[mi][1] = __builtin_amdgcn_mfma_f32_16x16x32_bf16(afr, bfr[1], acc[mi][1], 0, 0, 0);
      }
    }
    // store: q,k -> sQKt [n][o] transposed; v -> sVn [o-256][n]
    #pragma unroll
    for (int mi = 0; mi < 6; ++mi) {
      #pragma unroll
      for (int r = 0; r < 4; ++r) {
        int o = 96 * w + mi * 16 + 4 * g + r;
        float qb = qkv_b[o];
        #pragma unroll
        for (int ct = 0; ct < 2; ++ct) {
          int n = ct * 16 + l15;
          u16 hv = f2b(acc[mi][ct][r] + qb);
          if (o < 256) sQKt[(n * 256 + o) ^ ((n & 7) << 3)] = hv;
          else         sVn[(o - 256) * 40 + n] = hv;
        }
      }
    }
  }
  __syncthreads();

  // ---- phase 2: per-head attention (wave w owns head h=w)
  {
    const int h = w;
    const f32x4 zf = (f32x4){0.f, 0.f, 0.f, 0.f};
    bf16x8 qf[2], kf[2];
    #pragma unroll
    for (int t2 = 0; t2 < 2; ++t2) {
      int n = t2 * 16 + l15;
      qf[t2] = *(const bf16x8*)&sQKt[(n * 256 + h * 32 + 8 * g) ^ ((n & 7) << 3)];
      kf[t2] = *(const bf16x8*)&sQKt[(n * 256 + 128 + h * 32 + 8 * g) ^ ((n & 7) << 3)];
    }
    f32x4 sacc[2][2];
    #pragma unroll
    for (int tn = 0; tn < 2; ++tn)
      #pragma unroll
      for (int tm = 0; tm < 2; ++tm)
        sacc[tn][tm] = __builtin_amdgcn_mfma_f32_16x16x32_bf16(qf[tn], kf[tm], zf, 0, 0, 0);

    u16* sPw = &sP[w * 32 * 40];
    #pragma unroll
    for (int tn = 0; tn < 2; ++tn) {
      #pragma unroll
      for (int r = 0; r < 4; ++r) {
        int n = tn * 16 + 4 * g + r;
        float v0 = sacc[tn][0][r] * SCALE_F + rel[(l15      - n + 31) * 4 + h];
        float v1 = sacc[tn][1][r] * SCALE_F + rel[(16 + l15 - n + 31) * 4 + h];
        float mx = fmaxf(v0, v1);
        #pragma unroll
        for (int msk = 1; msk < 16; msk <<= 1) mx = fmaxf(mx, __shfl_xor(mx, msk));
        float e0 = __expf(v0 - mx), e1 = __expf(v1 - mx);
        float sm = e0 + e1;
        #pragma unroll
        for (int msk = 1; msk < 16; msk <<= 1) sm += __shfl_xor(sm, msk);
        float rinv = 1.0f / sm;
        sPw[n * 40 + l15]      = f2b(e0 * rinv);
        sPw[n * 40 + 16 + l15] = f2b(e1 * rinv);
      }
    }
    __syncthreads();   // orders P u16-stores vs b128 reloads (and all waves are here)

    bf16x8 pf[2], vf[2];
    #pragma unroll
    for (int t2 = 0; t2 < 2; ++t2) {
      pf[t2] = *(const bf16x8*)&sPw[(t2 * 16 + l15) * 40 + 8 * g];
      vf[t2] = *(const bf16x8*)&sVn[(h * 32 + t2 * 16 + l15) * 40 + 8 * g];
    }
    f32x4 oacc[2][2];
    #pragma unroll
    for (int tn = 0; tn < 2; ++tn)
      #pragma unroll
      for (int td = 0; td < 2; ++td)
        oacc[tn][td] = __builtin_amdgcn_mfma_f32_16x16x32_bf16(pf[tn], vf[td], zf, 0, 0, 0);

    // O^T -> sXt (x stage is dead): [n][c=h*32+d]
    #pragma unroll
    for (int tn = 0; tn < 2; ++tn)
      #pragma unroll
      for (int td = 0; td < 2; ++td)
        #pragma unroll
        for (int r = 0; r < 4; ++r) {
          int n = tn * 16 + 4 * g + r;
          int c = h * 32 + td * 16 + l15;
          sXt[(n * 128 + c) ^ ((n & 7) << 3)] = f2b(oacc[tn][td][r]);
        }
  }
  __syncthreads();

  // ---- phase 3: out-proj + residual + pre-BN store + channel stats
  {
    f32x4 pacc[2][2];
    #pragma unroll
    for (int mi = 0; mi < 2; ++mi)
      #pragma unroll
      for (int ct = 0; ct < 2; ++ct)
        pacc[mi][ct] = (f32x4){0.f, 0.f, 0.f, 0.f};

    #pragma unroll
    for (int kk = 0; kk < 4; ++kk) {
      bf16x8 bfr[2];
      #pragma unroll
      for (int ct = 0; ct < 2; ++ct) {
        int n = ct * 16 + l15;
        bfr[ct] = *(const bf16x8*)&sXt[(n * 128 + kk * 32 + 8 * g) ^ ((n & 7) << 3)];
      }
      #pragma unroll
      for (int mi = 0; mi < 2; ++mi) {
        int row = 32 * w + mi * 16 + l15;
        bf16x8 afr = *(const bf16x8*)&wo[row * 128 + kk * 32 + 8 * g];
        #pragma unroll
        for (int ct = 0; ct < 2; ++ct)
          pacc[mi][ct] = __builtin_amdgcn_mfma_f32_16x16x32_bf16(afr, bfr[ct], pacc[mi][ct], 0, 0, 0);
      }
    }

    float* ob = out + (size_t)b * (CH * NB);
    #pragma unroll
    for (int mi = 0; mi < 2; ++mi) {
      #pragma unroll
      for (int r = 0; r < 4; ++r) {
        int o = 32 * w + mi * 16 + 4 * g + r;
        float bias = out_b[o];
        float ssum = 0.f, ssq = 0.f;
        #pragma unroll
        for (int ct = 0; ct < 2; ++ct) {
          int n = ct * 16 + l15;
          float val = pacc[mi][ct][r] + bias + xb[o * NB + n];
          ob[o * NB + n] = val;
          ssum += val; ssq += val * val;
        }
        #pragma unroll
        for (int msk = 1; msk < 16; msk <<= 1) {
          ssum += __shfl_xor(ssum, msk);
          ssq  += __shfl_xor(ssq, msk);
        }
        if (l15 == 0) {
          atomicAdd(&stats[(b & 31) * 128 + o], ssum);
          atomicAdd(&stats[4096 + (b & 31) * 128 + o], ssq);
        }
      }
    }
  }
}

// ------------------------------------------------------------- BN stats ---
__global__ void bnstats_kernel(const float* __restrict__ stats,
                               const float* __restrict__ gamma,
                               const float* __restrict__ beta,
                               float* __restrict__ sc, float* __restrict__ sh,
                               float invM) {
  int c = threadIdx.x;
  if (c >= 128) return;
  float s = 0.f, q = 0.f;
  #pragma unroll 8
  for (int i = 0; i < 32; ++i) {
    s += stats[i * 128 + c];
    q += stats[4096 + i * 128 + c];
  }
  float mean = s * invM;
  float var  = q * invM - mean * mean;
  float rstd = rsqrtf(var + 1e-5f);
  float a = gamma[c] * rstd;
  sc[c] = a;
  sh[c] = beta[c] - mean * a;
}

// ------------------------------------------------------------- BN apply ---
__global__ __launch_bounds__(256) void bnapply_kernel(float* __restrict__ out,
                                                      const float* __restrict__ sc,
                                                      const float* __restrict__ sh,
                                                      int n4total) {
  int i = blockIdx.x * 256 + threadIdx.x;
  int stride = gridDim.x * 256;
  for (; i < n4total; i += stride) {
    int c = (i >> 3) & 127;
    float a = sc[c], d = sh[c];
    float4 v = ((float4*)out)[i];
    v.x = v.x * a + d;
    v.y = v.y * a + d;
    v.z = v.z * a + d;
    v.w = v.w * a + d;
    ((float4*)out)[i] = v;
  }
}

// --------------------------------------------------------------- launch ---
extern "C" void kernel_launch(void* const* d_in, const int* in_sizes, int n_in,
                              void* d_out, int out_size, void* d_ws, size_t ws_size,
                              hipStream_t stream) {
  const float* x     = (const float*)d_in[0];
  const float* qkv_w = (const float*)d_in[1];
  const float* qkv_b = (const float*)d_in[2];
  const float* out_w = (const float*)d_in[3];
  const float* out_b = (const float*)d_in[4];
  const float* rel   = (const float*)d_in[5];
  const float* gamma = (const float*)d_in[6];
  const float* beta  = (const float*)d_in[7];
  float* out = (float*)d_out;

  const int B = in_sizes[0] / (CH * NB);      // 8192

  u16* wq = (u16*)d_ws;                       // [384*128] bf16
  u16* wo = wq + 49152;                       // [128*128] bf16
  float* stats = (float*)(wo + 16384);        // 32 slots * 128 (sum) + same (sumsq)
  float* sc = stats + 8192;
  float* sh = sc + 128;

  prep_kernel<<<192, 256, 0, stream>>>(qkv_w, out_w, wq, wo, stats);
  attn_kernel<<<B, 256, 0, stream>>>(x, wq, qkv_b, wo, out_b, rel, out, stats);
  bnstats_kernel<<<1, 128, 0, stream>>>(stats, gamma, beta, sc, sh, 1.0f / (float)(B * NB));
  bnapply_kernel<<<2048, 256, 0, stream>>>(out, sc, sh, out_size / 4);
}

// Round 3
// 429.991 us; speedup vs baseline: 1.0957x; 1.0957x over previous
//
#include <hip/hip_runtime.h>
#include <hip/hip_bf16.h>

typedef unsigned short u16;
typedef __bf16 bf16x8 __attribute__((ext_vector_type(8)));
typedef float f32x4 __attribute__((ext_vector_type(4)));

#define CH 128
#define NB 32
#define SCALE_F 0.17677669529663687f

__device__ __forceinline__ u16 f2b(float f) {
  union { float f; unsigned u; } v; v.f = f;
  unsigned r = v.u + 0x7fffu + ((v.u >> 16) & 1u);
  return (u16)(r >> 16);
}

// ---------------------------------------------------------------- prep ----
__global__ void prep_kernel(const float* __restrict__ qw, const float* __restrict__ ow,
                            u16* __restrict__ wq, u16* __restrict__ wo,
                            float* __restrict__ stats) {
  int t = blockIdx.x * 256 + threadIdx.x;           // 192 blocks
  if (t < 49152) wq[t] = f2b(qw[t]);
  if (t < 16384) wo[t] = f2b(ow[t]);
  if (t < 8192)  stats[t] = 0.0f;
}

// ------------------------------------------------------------ main pass ---
// 1 block = 1 sample, 4 waves, wave w owns head w. Two barriers.
__global__ __launch_bounds__(256, 4) void attn_kernel(
    const float* __restrict__ x, const u16* __restrict__ wq,
    const float* __restrict__ qkv_b, const u16* __restrict__ wo,
    const float* __restrict__ out_b, const float* __restrict__ rel,
    float* __restrict__ out, float* __restrict__ stats) {

  // 36864 B total -> 4 blocks/CU
  __shared__ __attribute__((aligned(16))) u16 sQKt[32 * 256];   // [n][o] o<128:q, >=128:k; XOR swz
  __shared__ __attribute__((aligned(16))) u16 sVn[4][32 * 40];  // per-wave V [d][m]
  __shared__ __attribute__((aligned(16))) u16 sPO[4][32 * 40];  // per-wave P [n][m]; later sO [n][c] swz

  const int tid = threadIdx.x;
  const int w = tid >> 6, lane = tid & 63;
  const int g = lane >> 4, l15 = lane & 15;
  const int b = blockIdx.x, h = w;
  const float* xb = x + (size_t)b * (CH * NB);
  const f32x4 zf = {0.f, 0.f, 0.f, 0.f};

  // lane-resident rel-pos table: lane L holds rel[L][h]
  const float relv = rel[(lane < 63 ? lane : 62) * 4 + h];

  // ---- phase 1: QKV rows of head h only: 6 row-tiles (q,k,v x 2 d-tiles)
  f32x4 acc[6][2];
  #pragma unroll
  for (int tt = 0; tt < 6; ++tt)
    #pragma unroll
    for (int ct = 0; ct < 2; ++ct) acc[tt][ct] = zf;

  #pragma unroll
  for (int kk = 0; kk < 4; ++kk) {
    bf16x8 bfr[2];
    #pragma unroll
    for (int ct = 0; ct < 2; ++ct) {
      float xv[8];
      #pragma unroll
      for (int j = 0; j < 8; ++j)
        xv[j] = xb[(kk * 32 + 8 * g + j) * NB + 16 * ct + l15];
      union { bf16x8 v; unsigned u[4]; } uu;
      #pragma unroll
      for (int m = 0; m < 4; ++m)
        uu.u[m] = (unsigned)f2b(xv[2 * m]) | ((unsigned)f2b(xv[2 * m + 1]) << 16);
      bfr[ct] = uu.v;
    }
    #pragma unroll
    for (int tt = 0; tt < 6; ++tt) {
      const int part = tt >> 1, td = tt & 1;         // part 0=q 1=k 2=v
      const int row = part * 128 + h * 32 + 16 * td + l15;
      bf16x8 afr = *(const bf16x8*)&wq[row * 128 + kk * 32 + 8 * g];
      acc[tt][0] = __builtin_amdgcn_mfma_f32_16x16x32_bf16(afr, bfr[0], acc[tt][0], 0, 0, 0);
      acc[tt][1] = __builtin_amdgcn_mfma_f32_16x16x32_bf16(afr, bfr[1], acc[tt][1], 0, 0, 0);
    }
  }

  // ---- phase 2a: +bias; q,k -> sQKt (transposed, swz); v -> sVn[w] [d][m]
  #pragma unroll
  for (int tt = 0; tt < 6; ++tt) {
    const int part = tt >> 1, td = tt & 1;
    #pragma unroll
    for (int r = 0; r < 4; ++r) {
      const int d = 16 * td + 4 * g + r;
      const int orow = part * 128 + h * 32 + d;      // global qkv row
      const float bias = qkv_b[orow];
      #pragma unroll
      for (int ct = 0; ct < 2; ++ct) {
        const int n = 16 * ct + l15;
        const u16 hv = f2b(acc[tt][ct][r] + bias);
        if (part < 2) sQKt[(n * 256 + orow) ^ ((n & 7) << 3)] = hv;
        else          sVn[w][d * 40 + n] = hv;
      }
    }
  }
  // wave-private LDS: compiler orders ds_write->ds_read within the wave

  // ---- phase 2b: S = Q @ K^T (A: query rows, B: key cols)
  bf16x8 qf[2], kf[2];
  #pragma unroll
  for (int t2 = 0; t2 < 2; ++t2) {
    const int n = 16 * t2 + l15;
    qf[t2] = *(const bf16x8*)&sQKt[(n * 256 + h * 32 + 8 * g) ^ ((n & 7) << 3)];
    kf[t2] = *(const bf16x8*)&sQKt[(n * 256 + 128 + h * 32 + 8 * g) ^ ((n & 7) << 3)];
  }
  f32x4 sacc[2][2];   // [tn: q-tile][tm: k-tile]; C: col=l15 key, row=4g+r query
  #pragma unroll
  for (int tn = 0; tn < 2; ++tn)
    #pragma unroll
    for (int tm = 0; tm < 2; ++tm)
      sacc[tn][tm] = __builtin_amdgcn_mfma_f32_16x16x32_bf16(qf[tn], kf[tm], zf, 0, 0, 0);

  // ---- phase 2c: softmax over keys (16-lane xor reduce), bias via shfl
  u16* sPw = sPO[w];
  #pragma unroll
  for (int tn = 0; tn < 2; ++tn) {
    #pragma unroll
    for (int r = 0; r < 4; ++r) {
      const int n = 16 * tn + 4 * g + r;             // query index
      float v0 = sacc[tn][0][r] * SCALE_F + __shfl(relv, l15 - n + 31);
      float v1 = sacc[tn][1][r] * SCALE_F + __shfl(relv, 16 + l15 - n + 31);
      float mx = fmaxf(v0, v1);
      #pragma unroll
      for (int msk = 1; msk < 16; msk <<= 1) mx = fmaxf(mx, __shfl_xor(mx, msk));
      float e0 = __expf(v0 - mx), e1 = __expf(v1 - mx);
      float sm = e0 + e1;
      #pragma unroll
      for (int msk = 1; msk < 16; msk <<= 1) sm += __shfl_xor(sm, msk);
      const float ri = 1.0f / sm;
      sPw[n * 40 + l15]      = f2b(e0 * ri);
      sPw[n * 40 + 16 + l15] = f2b(e1 * ri);
    }
  }

  // ---- phase 2d: O = P @ V^T (A: P rows n, B: V cols d, k = keys)
  bf16x8 pf[2], vf[2];
  #pragma unroll
  for (int t2 = 0; t2 < 2; ++t2) {
    pf[t2] = *(const bf16x8*)&sPw[(16 * t2 + l15) * 40 + 8 * g];
    vf[t2] = *(const bf16x8*)&sVn[w][(16 * t2 + l15) * 40 + 8 * g];
  }
  f32x4 oacc[2][2];   // [tn][td]; C: col=l15 d, row=4g+r n
  #pragma unroll
  for (int tn = 0; tn < 2; ++tn)
    #pragma unroll
    for (int td = 0; td < 2; ++td)
      oacc[tn][td] = __builtin_amdgcn_mfma_f32_16x16x32_bf16(pf[tn], vf[td], zf, 0, 0, 0);

  __syncthreads();   // #1: all waves' P/V LDS reads drained before sO overwrites sP pool

  u16* sO = &sPO[0][0];   // O^T [n][c], XOR swz, 4096 u16
  #pragma unroll
  for (int tn = 0; tn < 2; ++tn)
    #pragma unroll
    for (int td = 0; td < 2; ++td)
      #pragma unroll
      for (int r = 0; r < 4; ++r) {
        const int n = 16 * tn + 4 * g + r;
        const int c = h * 32 + 16 * td + l15;
        sO[(n * 128 + c) ^ ((n & 7) << 3)] = f2b(oacc[tn][td][r]);
      }

  __syncthreads();   // #2: sO complete before cross-wave out-proj

  // ---- phase 3: out-proj rows 32w..32w+31 + residual + stats
  f32x4 pacc[2][2];
  #pragma unroll
  for (int mi = 0; mi < 2; ++mi)
    #pragma unroll
    for (int ct = 0; ct < 2; ++ct) pacc[mi][ct] = zf;

  #pragma unroll
  for (int kk = 0; kk < 4; ++kk) {
    bf16x8 bfr[2];
    #pragma unroll
    for (int ct = 0; ct < 2; ++ct) {
      const int n = 16 * ct + l15;
      bfr[ct] = *(const bf16x8*)&sO[(n * 128 + kk * 32 + 8 * g) ^ ((n & 7) << 3)];
    }
    #pragma unroll
    for (int mi = 0; mi < 2; ++mi) {
      const int row = 32 * w + 16 * mi + l15;
      bf16x8 afr = *(const bf16x8*)&wo[row * 128 + kk * 32 + 8 * g];
      pacc[mi][0] = __builtin_amdgcn_mfma_f32_16x16x32_bf16(afr, bfr[0], pacc[mi][0], 0, 0, 0);
      pacc[mi][1] = __builtin_amdgcn_mfma_f32_16x16x32_bf16(afr, bfr[1], pacc[mi][1], 0, 0, 0);
    }
  }

  float* ob = out + (size_t)b * (CH * NB);
  #pragma unroll
  for (int mi = 0; mi < 2; ++mi) {
    #pragma unroll
    for (int r = 0; r < 4; ++r) {
      const int o = 32 * w + 16 * mi + 4 * g + r;
      const float bias = out_b[o];
      float ssum = 0.f, ssq = 0.f;
      #pragma unroll
      for (int ct = 0; ct < 2; ++ct) {
        const int n = 16 * ct + l15;
        const float val = pacc[mi][ct][r] + bias + xb[o * NB + n];
        ob[o * NB + n] = val;
        ssum += val; ssq += val * val;
      }
      #pragma unroll
      for (int msk = 1; msk < 16; msk <<= 1) {
        ssum += __shfl_xor(ssum, msk);
        ssq  += __shfl_xor(ssq, msk);
      }
      if (l15 == 0) {
        atomicAdd(&stats[(b & 31) * 128 + o], ssum);
        atomicAdd(&stats[4096 + (b & 31) * 128 + o], ssq);
      }
    }
  }
}

// ------------------------------------------------------------- BN stats ---
__global__ void bnstats_kernel(const float* __restrict__ stats,
                               const float* __restrict__ gamma,
                               const float* __restrict__ beta,
                               float* __restrict__ sc, float* __restrict__ sh,
                               float invM) {
  int c = threadIdx.x;
  if (c >= 128) return;
  float s = 0.f, q = 0.f;
  #pragma unroll 8
  for (int i = 0; i < 32; ++i) {
    s += stats[i * 128 + c];
    q += stats[4096 + i * 128 + c];
  }
  float mean = s * invM;
  float var  = q * invM - mean * mean;
  float rstd = rsqrtf(var + 1e-5f);
  float a = gamma[c] * rstd;
  sc[c] = a;
  sh[c] = beta[c] - mean * a;
}

// ------------------------------------------------------------- BN apply ---
__global__ __launch_bounds__(256) void bnapply_kernel(float* __restrict__ out,
                                                      const float* __restrict__ sc,
                                                      const float* __restrict__ sh,
                                                      int n4total) {
  int i = blockIdx.x * 256 + threadIdx.x;
  int stride = gridDim.x * 256;
  for (; i < n4total; i += stride) {
    int c = (i >> 3) & 127;
    float a = sc[c], d = sh[c];
    float4 v = ((float4*)out)[i];
    v.x = v.x * a + d;
    v.y = v.y * a + d;
    v.z = v.z * a + d;
    v.w = v.w * a + d;
    ((float4*)out)[i] = v;
  }
}

// --------------------------------------------------------------- launch ---
extern "C" void kernel_launch(void* const* d_in, const int* in_sizes, int n_in,
                              void* d_out, int out_size, void* d_ws, size_t ws_size,
                              hipStream_t stream) {
  const float* x     = (const float*)d_in[0];
  const float* qkv_w = (const float*)d_in[1];
  const float* qkv_b = (const float*)d_in[2];
  const float* out_w = (const float*)d_in[3];
  const float* out_b = (const float*)d_in[4];
  const float* rel   = (const float*)d_in[5];
  const float* gamma = (const float*)d_in[6];
  const float* beta  = (const float*)d_in[7];
  float* out = (float*)d_out;

  const int B = in_sizes[0] / (CH * NB);      // 8192

  u16* wq = (u16*)d_ws;                       // [384*128] bf16
  u16* wo = wq + 49152;                       // [128*128] bf16
  float* stats = (float*)(wo + 16384);        // 32 slots x 128 sum + sumsq
  float* sc = stats + 8192;
  float* sh = sc + 128;

  prep_kernel<<<192, 256, 0, stream>>>(qkv_w, out_w, wq, wo, stats);
  attn_kernel<<<B, 256, 0, stream>>>(x, wq, qkv_b, wo, out_b, rel, out, stats);
  bnstats_kernel<<<1, 128, 0, stream>>>(stats, gamma, beta, sc, sh, 1.0f / (float)(B * NB));
  bnapply_kernel<<<2048, 256, 0, stream>>>(out, sc, sh, out_size / 4);
}